// Round 7
// baseline (258.244 us; speedup 1.0000x reference)
//
#include <hip/hip_runtime.h>

typedef unsigned short ushort_t;
typedef __bf16 bf16x8 __attribute__((ext_vector_type(8)));
typedef float f32x4 __attribute__((ext_vector_type(4)));

#define T_DIM 2048
#define B_DIM 2
#define E_DIM 1024
#define H_DIM 8
#define R_DIM 2
#define D_DIM 128
#define M_WIN 96
#define SCALING 0.08838834764831845f   // D^-0.5
#define LN2F 0.69314718055994530942f

__device__ __forceinline__ float bfu(unsigned u) {
  union { unsigned i; float f; } x; x.i = u << 16; return x.f;
}
__device__ __forceinline__ unsigned f2bf(float f) {
  union { float f; unsigned i; } x; x.f = f;
  unsigned r = x.i + 0x7fffu + ((x.i >> 16) & 1u);
  return r >> 16;
}
__device__ __forceinline__ void gl_lds16(const void* g, void* l) {
  __builtin_amdgcn_global_load_lds(
      (const __attribute__((address_space(1))) unsigned int*)g,
      (__attribute__((address_space(3))) unsigned int*)l, 16, 0, 0);
}

// ---------------------------------------------------------------------------
// prep2: packA (8192 blocks) + packT (768) + fuseF (64) + zero snorm (1).
// Register-capped: launch_bounds(256,4) => <=128 VGPR; fuseF loop unroll 2
// (the r5 merge died at 224 VGPR / 2 waves per EU from full unroll).
// ---------------------------------------------------------------------------
__global__ __launch_bounds__(256, 4) void prep2_kernel(
    const float* __restrict__ query, const float* __restrict__ value,
    const float* __restrict__ Wq, const float* __restrict__ Wv,
    const float* __restrict__ Wo, const float* __restrict__ bq,
    const float* __restrict__ hw,
    ushort_t* __restrict__ qh, ushort_t* __restrict__ vh,
    ushort_t* __restrict__ WqT, ushort_t* __restrict__ WvT,
    ushort_t* __restrict__ WoT, float* __restrict__ F,
    float* __restrict__ cvec, float* __restrict__ snorm)
{
  __shared__ float plds[4160];
  const int bid = blockIdx.x, tid = threadIdx.x;
  if (bid < 8192) {                     // ---- packA ----
    const float* src = (bid < 4096) ? query : value;
    ushort_t* dst = (bid < 4096) ? qh : vh;
    int i = ((bid & 4095) * 256 + tid) * 4;
    float4 x = *(const float4*)&src[i];
    uint2 oh;
    oh.x = f2bf(x.x) | (f2bf(x.y) << 16);
    oh.y = f2bf(x.z) | (f2bf(x.w) << 16);
    *(uint2*)&dst[i] = oh;
  } else if (bid < 8960) {              // ---- packT ----
    int idx = bid - 8192;
    const float* in = (idx < 256) ? Wq : (idx < 512) ? Wv : Wo;
    ushort_t* hi = (idx < 256) ? WqT : (idx < 512) ? WvT : WoT;
    int tile = idx & 255;
    int n0 = (tile & 15) * 64, k0 = (tile >> 4) * 64;
    float (*t64)[65] = (float(*)[65])plds;
    const int tr = tid >> 4, tc4 = (tid & 15) * 4;
#pragma unroll
    for (int rr = 0; rr < 64; rr += 16)
      *(float4*)&t64[tr + rr][tc4] = *(const float4*)&in[(size_t)(k0 + tr + rr) * E_DIM + n0 + tc4];
    __syncthreads();
#pragma unroll
    for (int rr = 0; rr < 64; rr += 16) {
      int n = n0 + tr + rr;
      uint2 oh;
      oh.x = f2bf(t64[tc4 + 0][tr + rr]) | (f2bf(t64[tc4 + 1][tr + rr]) << 16);
      oh.y = f2bf(t64[tc4 + 2][tr + rr]) | (f2bf(t64[tc4 + 3][tr + rr]) << 16);
      *(uint2*)&hi[(size_t)n * E_DIM + k0 + tc4] = oh;
    }
  } else if (bid < 9024) {              // ---- fuseF ----
    float* wl = plds;                   // [512]
    const int rh = (bid - 8960) & 15, h = rh & 7;
    const int e = ((bid - 8960) >> 4) * 256 + tid;
    for (int i = tid; i < 512; i += 256) wl[i] = hw[rh * 512 + i];
    __syncthreads();
    const float* wr = Wq + (size_t)e * E_DIM + h * D_DIM;
    float a0 = 0.f, a1 = 0.f, a2 = 0.f, a3 = 0.f;
#pragma unroll 2
    for (int d = 0; d < 128; d += 2) {
      float2 q2 = *(const float2*)&wr[d];
      float4 w0 = *(const float4*)&wl[d * 4];
      float4 w1 = *(const float4*)&wl[d * 4 + 4];
      a0 += q2.x * w0.x + q2.y * w1.x;
      a1 += q2.x * w0.y + q2.y * w1.y;
      a2 += q2.x * w0.z + q2.y * w1.z;
      a3 += q2.x * w0.w + q2.y * w1.w;
    }
    float4 o; o.x = a0; o.y = a1; o.z = a2; o.w = a3;
    *(float4*)&F[(size_t)e * 64 + rh * 4] = o;
    if ((bid - 8960) < 16 && tid < 4) {
      float acc = 0.f;
#pragma unroll 1
      for (int d = 0; d < 128; ++d) acc += bq[h * D_DIM + d] * wl[d * 4 + tid];
      cvec[rh * 4 + tid] = acc;
    }
  } else {                              // ---- zero snorm ----
    float4 z4 = {0.f, 0.f, 0.f, 0.f};
#pragma unroll
    for (int i = 0; i < 4; ++i)
      *(float4*)&snorm[(i * 256 + tid) * 4] = z4;
  }
}

// ---------------------------------------------------------------------------
// hashlin: lin[row][64] = query@F + c (fp32), fused argmax -> hashb.
// ---------------------------------------------------------------------------
__global__ __launch_bounds__(256) void hashlin_kernel(const float* __restrict__ query,
                                                      const float* __restrict__ F,
                                                      const float* __restrict__ cvec,
                                                      int* __restrict__ hashb)
{
  __shared__ float As[32][17];
  __shared__ float Fs[32][64];
  const int tid = threadIdx.x;
  const int ty = tid >> 4, tx = tid & 15;
  const int r0 = blockIdx.x * 16;
  float acc0 = 0.f, acc1 = 0.f, acc2 = 0.f, acc3 = 0.f;
  for (int k0 = 0; k0 < E_DIM; k0 += 32) {
    __syncthreads();
    {
      int i = tid * 2, row = i >> 5, kk = i & 31;
      float2 a2 = *(const float2*)&query[(size_t)(r0 + row) * E_DIM + k0 + kk];
      As[kk][row] = a2.x; As[kk + 1][row] = a2.y;
    }
    {
      int i = tid * 8, kk = i >> 6, cc = i & 63;
      float4 f0 = *(const float4*)&F[(size_t)(k0 + kk) * 64 + cc];
      float4 f1 = *(const float4*)&F[(size_t)(k0 + kk) * 64 + cc + 4];
      *(float4*)&Fs[kk][cc] = f0;
      *(float4*)&Fs[kk][cc + 4] = f1;
    }
    __syncthreads();
#pragma unroll
    for (int kk = 0; kk < 32; ++kk) {
      float a = As[kk][ty];
      float4 f4 = *(const float4*)&Fs[kk][tx * 4];
      acc0 += a * f4.x; acc1 += a * f4.y; acc2 += a * f4.z; acc3 += a * f4.w;
    }
  }
  float4 c4 = *(const float4*)&cvec[tx * 4];
  float lin[4] = {acc0 + c4.x, acc1 + c4.y, acc2 + c4.z, acc3 + c4.w};
  float best = lin[0]; int bi = 0;
#pragma unroll
  for (int idx = 1; idx < 8; ++idx) {
    float v = (idx < 4) ? lin[idx] : -lin[idx - 4];
    if (v > best) { best = v; bi = idx; }   // first-occurrence argmax
  }
  int grow = r0 + ty;             // t*B + b
  int t = grow >> 1, b = grow & 1;
  int rr = tx >> 3, hh = tx & 7;
  hashb[(size_t)((b * R_DIM + rr) * H_DIM + hh) * T_DIM + t] = bi;
}

// ---------------------------------------------------------------------------
// MFMA GEMM 4096x1024x1024, tile 128x128, BK=32, gl_lds(16B) staging.
// z selects problem. Cb!=null -> bf16 out, else fp32 to Cf.
// do_norm: on z==0, accumulate row sum-of-squares of bf16-rounded output
// into snorm via lane-shuffle reduction + one atomicAdd per (row, wave).
// ---------------------------------------------------------------------------
__global__ __launch_bounds__(256) void gemm_mfma(
    const ushort_t* __restrict__ A0, const ushort_t* __restrict__ B0,
    const float* __restrict__ bias0, ushort_t* __restrict__ Cb0, float* __restrict__ Cf0,
    const ushort_t* __restrict__ A1, const ushort_t* __restrict__ B1,
    const float* __restrict__ bias1, ushort_t* __restrict__ Cb1, float* __restrict__ Cf1,
    float* __restrict__ snorm, int do_norm)
{
  const ushort_t* Ah = blockIdx.z ? A1 : A0;
  const ushort_t* Bh = blockIdx.z ? B1 : B0;
  const float* bias = blockIdx.z ? bias1 : bias0;
  ushort_t* Cb = blockIdx.z ? Cb1 : Cb0;
  float* Cf = blockIdx.z ? Cf1 : Cf0;

  __shared__ ushort_t As[128 * 32];
  __shared__ ushort_t Bs[128 * 32];
  const int tid = threadIdx.x, w = tid >> 6, lane = tid & 63;
  const int lm = lane & 15, quad = lane >> 4;
  const int wr = w >> 1, wc = w & 1;
  const int m0 = blockIdx.y * 128, n0 = blockIdx.x * 128;
  const int lrow = lane >> 2, lcol = (lane & 3) * 8;

  f32x4 acc[4][4] = {};

  for (int k0 = 0; k0 < E_DIM; k0 += 32) {
    __syncthreads();
#pragma unroll
    for (int k = 0; k < 8; ++k) {
      if ((k & 3) == w) {
        gl_lds16(Ah + (size_t)(m0 + k * 16 + lrow) * E_DIM + k0 + lcol, &As[k * 512]);
        gl_lds16(Bh + (size_t)(n0 + k * 16 + lrow) * E_DIM + k0 + lcol, &Bs[k * 512]);
      }
    }
    __syncthreads();
    bf16x8 av[4], bv[4];
#pragma unroll
    for (int i = 0; i < 4; ++i) av[i] = *(const bf16x8*)&As[(wr * 64 + i * 16 + lm) * 32 + quad * 8];
#pragma unroll
    for (int j = 0; j < 4; ++j) bv[j] = *(const bf16x8*)&Bs[(wc * 64 + j * 16 + lm) * 32 + quad * 8];
#pragma unroll
    for (int i = 0; i < 4; ++i)
#pragma unroll
      for (int j = 0; j < 4; ++j)
        acc[i][j] = __builtin_amdgcn_mfma_f32_16x16x32_bf16(av[i], bv[j], acc[i][j], 0, 0, 0);
  }

  float rs[4][4] = {};
#pragma unroll
  for (int j = 0; j < 4; ++j) {
    int col = n0 + wc * 64 + j * 16 + lm;
    float bj = bias[col];
#pragma unroll
    for (int i = 0; i < 4; ++i) {
      int rowb = m0 + wr * 64 + i * 16 + quad * 4;
#pragma unroll
      for (int rg = 0; rg < 4; ++rg) {
        float val = acc[i][j][rg] + bj;
        if (Cb) {
          unsigned ub = f2bf(val);
          Cb[(size_t)(rowb + rg) * E_DIM + col] = (ushort_t)ub;
          float vb = bfu(ub);
          rs[i][rg] += vb * vb;
        } else {
          Cf[(size_t)(rowb + rg) * E_DIM + col] = val;
        }
      }
    }
  }
  if (do_norm && blockIdx.z == 0) {
#pragma unroll
    for (int i = 0; i < 4; ++i)
#pragma unroll
      for (int rg = 0; rg < 4; ++rg) {
        float s = rs[i][rg];
        s += __shfl_xor(s, 1);
        s += __shfl_xor(s, 2);
        s += __shfl_xor(s, 4);
        s += __shfl_xor(s, 8);
        if (lm == 0)
          atomicAdd(&snorm[m0 + wr * 64 + i * 16 + quad * 4 + rg], s);
      }
  }
}

// ---------------------------------------------------------------------------
// Stable counting sort by hash in [0,8) per (b,r,h). Parallel scan. 32 blocks.
// ---------------------------------------------------------------------------
__global__ __launch_bounds__(256) void sort_kernel(const int* __restrict__ hashb,
                                                   int* __restrict__ p, int* __restrict__ inv)
{
  const int bid = blockIdx.x, tid = threadIdx.x;
  const int lane = tid & 63, w = tid >> 6;
  const int* hrow = hashb + (size_t)bid * T_DIM;
  __shared__ int mat[8][256];
  __shared__ int btot[8], bbase[8];
  int cnt[8];
#pragma unroll
  for (int v = 0; v < 8; ++v) cnt[v] = 0;
  int hv[8];
#pragma unroll
  for (int j = 0; j < 8; ++j) { hv[j] = hrow[tid * 8 + j]; cnt[hv[j]]++; }
#pragma unroll
  for (int v = 0; v < 8; ++v) mat[v][tid] = cnt[v];
  __syncthreads();
  for (int v = w; v < 8; v += 4) {
    int4 c4 = *(const int4*)&mat[v][lane * 4];
    int s = c4.x + c4.y + c4.z + c4.w;
    int x = s;
    for (int off = 1; off < 64; off <<= 1) {
      int y = __shfl_up(x, off);
      if (lane >= off) x += y;
    }
    int excl = x - s;
    mat[v][lane * 4 + 0] = excl;
    mat[v][lane * 4 + 1] = excl + c4.x;
    mat[v][lane * 4 + 2] = excl + c4.x + c4.y;
    mat[v][lane * 4 + 3] = excl + c4.x + c4.y + c4.z;
    if (lane == 63) btot[v] = x;
  }
  __syncthreads();
  if (tid == 0) {
    int run = 0;
    for (int v = 0; v < 8; ++v) { bbase[v] = run; run += btot[v]; }
  }
  __syncthreads();
#pragma unroll
  for (int v = 0; v < 8; ++v) cnt[v] = 0;
#pragma unroll
  for (int j = 0; j < 8; ++j) {
    int v = hv[j];
    int pos = bbase[v] + mat[v][tid] + cnt[v];
    cnt[v]++;
    p[(size_t)bid * T_DIM + pos] = tid * 8 + j;
    inv[(size_t)bid * T_DIM + tid * 8 + j] = pos;
  }
}

// ---------------------------------------------------------------------------
// gather: per (c, brh): meta/invn in sorted order; ksort padded bf16 rows
// [pos][136]; vt transposed chunk tiles [d][32]. invn = 1/sqrt(snorm).
// ---------------------------------------------------------------------------
__global__ __launch_bounds__(256) void gather_kernel(
    const ushort_t* __restrict__ qfb, const ushort_t* __restrict__ vfb,
    const float* __restrict__ snorm, const int* __restrict__ hashb,
    const int* __restrict__ p, const int* __restrict__ inv,
    int* __restrict__ meta_s, float* __restrict__ invn_s,
    ushort_t* __restrict__ ksort, ushort_t* __restrict__ vt)
{
  const int c = blockIdx.x, brh = blockIdx.y;
  const int b = brh >> 4, h = brh & 7;
  const int brh_o = brh ^ 8;
  const int tid = threadIdx.x;
  __shared__ int ts[32];
  __shared__ ushort_t vtile[32 * 136];

  if (tid < 32) {
    int pos = c * 32 + tid;
    int t = p[(size_t)brh * T_DIM + pos];
    int hh = hashb[(size_t)brh * T_DIM + t];
    int co = inv[(size_t)brh_o * T_DIM + t] >> 5;
    meta_s[(size_t)brh * T_DIM + pos] = t | (hh << 11) | (co << 14);
    invn_s[(size_t)brh * T_DIM + pos] = 1.0f / sqrtf(snorm[t * B_DIM + b]);
    ts[tid] = t;
  }
  __syncthreads();
  {
    int i = tid >> 3, part = tid & 7;
    int t = ts[i];
    const ushort_t* src = qfb + ((size_t)(t * B_DIM + b) << 10) + h * D_DIM + part * 16;
    uint4 a = *(const uint4*)src;
    uint4 bb = *(const uint4*)(src + 8);
    ushort_t* dst = ksort + ((size_t)brh * T_DIM + c * 32 + i) * 136 + part * 16;
    *(uint4*)dst = a; *(uint4*)(dst + 8) = bb;
    const ushort_t* vsrc = vfb + ((size_t)(t * B_DIM + b) << 10) + h * D_DIM + part * 16;
    uint4 va = *(const uint4*)vsrc;
    uint4 vb = *(const uint4*)(vsrc + 8);
    ushort_t* vdst = &vtile[i * 136 + part * 16];
    *(uint4*)vdst = va; *(uint4*)(vdst + 8) = vb;
  }
  __syncthreads();
  {
    int d = tid >> 1, half = tid & 1;
    unsigned pk[8];
#pragma unroll
    for (int jj = 0; jj < 8; ++jj) {
      unsigned lo = vtile[(half * 16 + jj * 2) * 136 + d];
      unsigned hi = vtile[(half * 16 + jj * 2 + 1) * 136 + d];
      pk[jj] = lo | (hi << 16);
    }
    ushort_t* out = vt + ((size_t)(brh * 64 + c)) * 4096 + d * 32 + half * 16;
    uint4 o0; o0.x = pk[0]; o0.y = pk[1]; o0.z = pk[2]; o0.w = pk[3];
    uint4 o1; o1.x = pk[4]; o1.y = pk[5]; o1.z = pk[6]; o1.w = pk[7];
    *(uint4*)out = o0; *(uint4*)(out + 8) = o1;
  }
}

// ---------------------------------------------------------------------------
// attn: block per (c,h,b*2+r). All staging via global_load_lds from presorted
// ksort / vt. Q = middle 32 rows of K window. Scaling folded into epilogue.
// ---------------------------------------------------------------------------
__global__ __launch_bounds__(256) void attn_kernel(
    const ushort_t* __restrict__ ksort, const ushort_t* __restrict__ vt,
    const int* __restrict__ meta_s, const float* __restrict__ invn_s,
    ushort_t* __restrict__ o_out, float* __restrict__ z_out)
{
  const int c = blockIdx.x, h = blockIdx.y, bz = blockIdx.z;
  const int b = bz >> 1, r = bz & 1;
  const int brh = (b * R_DIM + r) * H_DIM + h;
  const int tid = threadIdx.x;
  const int lane = tid & 63, w = tid >> 6;
  const int lm = lane & 15, quad = lane >> 4;

  // Kw[96][136]us @0 (26112 B); VT 3x[128][32]us @26112 (24576 B)
  // SS[32][100]f32 overlays @0; Ps[32][104]us @13312.
  __shared__ __align__(16) unsigned char smem[50688];
  ushort_t* Kw = (ushort_t*)smem;
  ushort_t* VTb = (ushort_t*)(smem + 26112);
  float*    SS = (float*)smem;
  ushort_t* Ps = (ushort_t*)(smem + 13312);
  __shared__ int skp[M_WIN];
  __shared__ float s_invn[M_WIN];

  int cjs[3] = {(c + 63) & 63, c, (c + 1) & 63};

  // --- bulk DMA staging (no VALU conversions) ---
  int cnt = 0;
#pragma unroll
  for (int j = 0; j < 3; ++j) {
    const ushort_t* gk = ksort + ((size_t)brh * T_DIM + cjs[j] * 32) * 136;
    ushort_t* lk = Kw + j * 4352;
#pragma unroll
    for (int k = 0; k < 8; ++k) {
      if ((cnt++ & 3) == w) gl_lds16(gk + k * 512 + lane * 8, lk + k * 512);
    }
    if ((cnt++ & 3) == w) {            // 512-B remainder of the 8704-B chunk
      if (lane < 32) gl_lds16(gk + 4096 + lane * 8, lk + 4096);
    }
  }
#pragma unroll
  for (int j = 0; j < 3; ++j) {
    const ushort_t* gv = vt + ((size_t)(brh * 64 + cjs[j])) * 4096;
    ushort_t* lv = VTb + j * 4096;
#pragma unroll
    for (int k = 0; k < 8; ++k) {
      if ((cnt++ & 3) == w) gl_lds16(gv + k * 512 + lane * 8, lv + k * 512);
    }
  }
  if (tid < M_WIN) {
    int pos = cjs[tid >> 5] * 32 + (tid & 31);
    skp[tid] = meta_s[(size_t)brh * T_DIM + pos];
    s_invn[tid] = invn_s[(size_t)brh * T_DIM + pos];
  }
  __syncthreads();   // drains gl_lds (vmcnt) + meta

  // --- QK^T MFMA: wave w -> m-tile (w&1), n-tiles (w>>1)*3+{0,1,2} ---
  const int mw = w & 1, nset = w >> 1;
  bf16x8 av[4];
#pragma unroll
  for (int kk = 0; kk < 4; ++kk)
    av[kk] = *(const bf16x8*)&Kw[(32 + mw * 16 + lm) * 136 + kk * 32 + quad * 8];
  f32x4 sacc[3] = {};
#pragma unroll
  for (int jj = 0; jj < 3; ++jj) {
    int nt = nset * 3 + jj;
#pragma unroll
    for (int kk = 0; kk < 4; ++kk) {
      bf16x8 bv = *(const bf16x8*)&Kw[(nt * 16 + lm) * 136 + kk * 32 + quad * 8];
      sacc[jj] = __builtin_amdgcn_mfma_f32_16x16x32_bf16(av[kk], bv, sacc[jj], 0, 0, 0);
    }
  }
  __syncthreads();   // Kw reads done; SS overlay safe

  // --- epilogue: scale + masks -> SS ---
  const int rowb = mw * 16 + quad * 4;
#pragma unroll
  for (int jj = 0; jj < 3; ++jj) {
    int col = (nset * 3 + jj) * 16 + lm;
    int kp = skp[col];
    float scl = SCALING * s_invn[col];
#pragma unroll
    for (int rg = 0; rg < 4; ++rg) {
      int qp = skp[32 + rowb + rg];
      float sc = sacc[jj][rg] * scl;
      if ((kp ^ qp) & 0x3800) sc -= 1.0e16f;       // mask_different_hashes
      if (!((kp ^ qp) & 0x7FF)) sc -= 1.0e8f;      // mask_current
      int dc = ((kp >> 14) - (qp >> 14)) & 63;
      if (dc <= 1 || dc == 63) sc -= LN2F;         // -log(dup)
      SS[(rowb + rg) * 100 + col] = sc;
    }
  }
  __syncthreads();

  // --- softmax (8 threads/row) -> Ps bf16, z ---
  {
    const int l = tid >> 3, g = tid & 7;
    float smy[12];
#pragma unroll
    for (int j = 0; j < 12; ++j) smy[j] = SS[l * 100 + g + 8 * j];
    float mx = smy[0];
#pragma unroll
    for (int j = 1; j < 12; ++j) mx = fmaxf(mx, smy[j]);
    mx = fmaxf(mx, __shfl_xor(mx, 1));
    mx = fmaxf(mx, __shfl_xor(mx, 2));
    mx = fmaxf(mx, __shfl_xor(mx, 4));
    float sum = 0.f, ey[12];
#pragma unroll
    for (int j = 0; j < 12; ++j) { ey[j] = expf(smy[j] - mx); sum += ey[j]; }
    sum += __shfl_xor(sum, 1);
    sum += __shfl_xor(sum, 2);
    sum += __shfl_xor(sum, 4);
    float inv_s = 1.0f / sum;
#pragma unroll
    for (int j = 0; j < 12; ++j)
      Ps[l * 104 + g + 8 * j] = (ushort_t)f2bf(ey[j] * inv_s);
    if (g == 0) z_out[(size_t)brh * T_DIM + (skp[32 + l] & 2047)] = mx + logf(sum);
  }
  __syncthreads();

  // --- PV MFMA: wave w -> m-tile (w&1), d-tiles (w>>1)*4+{0..3}; K=96 ---
  const int dset = w >> 1;
  bf16x8 pa[3];
#pragma unroll
  for (int kk = 0; kk < 3; ++kk)
    pa[kk] = *(const bf16x8*)&Ps[(mw * 16 + lm) * 104 + kk * 32 + quad * 8];
  f32x4 oacc[4] = {};
#pragma unroll
  for (int jj = 0; jj < 4; ++jj) {
    int dt = dset * 4 + jj;
#pragma unroll
    for (int kk = 0; kk < 3; ++kk) {
      const ushort_t* VTk = VTb + kk * 4096;
      bf16x8 bv = *(const bf16x8*)&VTk[(dt * 16 + lm) * 32 + quad * 8];
      oacc[jj] = __builtin_amdgcn_mfma_f32_16x16x32_bf16(pa[kk], bv, oacc[jj], 0, 0, 0);
    }
  }
#pragma unroll
  for (int jj = 0; jj < 4; ++jj) {
    int col = (dset * 4 + jj) * 16 + lm;
#pragma unroll
    for (int rg = 0; rg < 4; ++rg) {
      int tqo = skp[32 + rowb + rg] & 2047;
      o_out[((size_t)brh * T_DIM + tqo) * D_DIM + col] = (ushort_t)f2bf(oacc[jj][rg]);
    }
  }
}

// ---------------------------------------------------------------------------
// Combine rounds (bf16 o) -> ctx bf16.
// ---------------------------------------------------------------------------
__global__ __launch_bounds__(256) void combine_kernel(const ushort_t* __restrict__ obf,
                                                      const float* __restrict__ z_buf,
                                                      ushort_t* __restrict__ ctx)
{
  int gid = blockIdx.x * 256 + threadIdx.x;   // [0, 1048576)
  int d4 = gid & 31;
  int t = (gid >> 5) & (T_DIM - 1);
  int h = (gid >> 16) & 7;
  int b = gid >> 19;
  int brh0 = (b * R_DIM + 0) * H_DIM + h;
  int brh1 = brh0 + H_DIM;
  float z0 = z_buf[(size_t)brh0 * T_DIM + t], z1 = z_buf[(size_t)brh1 * T_DIM + t];
  float mz = fmaxf(z0, z1);
  float e0 = expf(z0 - mz), e1 = expf(z1 - mz);
  float is = 1.0f / (e0 + e1);
  float w0 = e0 * is, w1 = e1 * is;
  uint2 a = *(const uint2*)&obf[((size_t)brh0 * T_DIM + t) * D_DIM + d4 * 4];
  uint2 cc = *(const uint2*)&obf[((size_t)brh1 * T_DIM + t) * D_DIM + d4 * 4];
  uint2 o;
  o.x = f2bf(w0 * bfu(a.x & 0xffffu) + w1 * bfu(cc.x & 0xffffu)) |
        (f2bf(w0 * bfu(a.x >> 16) + w1 * bfu(cc.x >> 16)) << 16);
  o.y = f2bf(w0 * bfu(a.y & 0xffffu) + w1 * bfu(cc.y & 0xffffu)) |
        (f2bf(w0 * bfu(a.y >> 16) + w1 * bfu(cc.y >> 16)) << 16);
  *(uint2*)&ctx[((size_t)(t * B_DIM + b) << 10) + h * D_DIM + d4 * 4] = o;
}

// ---------------------------------------------------------------------------
extern "C" void kernel_launch(void* const* d_in, const int* in_sizes, int n_in,
                              void* d_out, int out_size, void* d_ws, size_t ws_size,
                              hipStream_t stream)
{
  const float* query = (const float*)d_in[0];
  // d_in[1] = key, unused (share_kq)
  const float* value = (const float*)d_in[2];
  const float* Wq = (const float*)d_in[3];
  const float* bq = (const float*)d_in[4];
  const float* Wv = (const float*)d_in[5];
  const float* bv = (const float*)d_in[6];
  const float* Wo = (const float*)d_in[7];
  const float* bo = (const float*)d_in[8];
  const float* hw = (const float*)d_in[9];

  float* ws = (float*)d_ws;
  ushort_t* qh    = (ushort_t*)ws;               // 4,194,304 us
  ushort_t* vh    = qh + 4194304;                // 4,194,304 us
  ushort_t* obuf  = qh;                          // overlay (dead after gemm z=2)
  ushort_t* qfb   = (ushort_t*)(ws + 4194304);   // 4,194,304 us
  ushort_t* ctx   = qfb;                         // overlay (qfb dead after gather)
  ushort_t* vfb   = qfb + 4194304;               // 4,194,304 us
  ushort_t* ksort = vfb + 4194304;               // 8,912,896 us
  ushort_t* vt    = ksort + 8912896;             // 8,388,608 us
  ushort_t* WqTh  = vt + 8388608;                // 1,048,576 us x3
  ushort_t* WvTh  = WqTh + 1048576;
  ushort_t* WoTh  = WvTh + 1048576;
  float* F        = (float*)(WoTh + 1048576);    // 65,536 f
  float* cvec     = F + 65536;                   // 64 f
  float* zbuf     = cvec + 64;                   // 65,536 f
  float* snorm    = zbuf + 65536;                // 4,096 f
  int* hashb      = (int*)(snorm + 4096);        // 65,536 i
  int* pperm      = hashb + 65536;
  int* pinv       = pperm + 65536;
  int* meta_s     = pinv + 65536;
  float* invn_s   = (float*)(meta_s + 65536);

  prep2_kernel<<<9025, 256, 0, stream>>>(query, value, Wq, Wv, Wo, bq, hw,
                                         qh, vh, WqTh, WvTh, WoTh, F, cvec, snorm);
  hashlin_kernel<<<256, 256, 0, stream>>>(query, F, cvec, hashb);
  gemm_mfma<<<dim3(8, 32, 2), 256, 0, stream>>>(qh, WqTh, bq, qfb, (float*)nullptr,
                                                vh, WvTh, bv, vfb, (float*)nullptr,
                                                snorm, 1);
  sort_kernel<<<32, 256, 0, stream>>>(hashb, pperm, pinv);
  gather_kernel<<<dim3(64, 32), 256, 0, stream>>>(qfb, vfb, snorm, hashb, pperm, pinv,
                                                  meta_s, invn_s, ksort, vt);
  attn_kernel<<<dim3(64, 8, 4), 256, 0, stream>>>(ksort, vt, meta_s, invn_s, obuf, zbuf);
  combine_kernel<<<4096, 256, 0, stream>>>(obuf, zbuf, ctx);
  gemm_mfma<<<dim3(8, 32, 1), 256, 0, stream>>>(ctx, WoTh, bo, (ushort_t*)nullptr, (float*)d_out,
                                                (const ushort_t*)nullptr, (const ushort_t*)nullptr,
                                                (const float*)nullptr, (ushort_t*)nullptr, (float*)nullptr,
                                                snorm, 0);
}

// Round 8
// 241.561 us; speedup vs baseline: 1.0691x; 1.0691x over previous
//
#include <hip/hip_runtime.h>

typedef unsigned short ushort_t;
typedef __bf16 bf16x8 __attribute__((ext_vector_type(8)));
typedef float f32x4 __attribute__((ext_vector_type(4)));

#define T_DIM 2048
#define B_DIM 2
#define E_DIM 1024
#define H_DIM 8
#define R_DIM 2
#define D_DIM 128
#define M_WIN 96
#define SCALING 0.08838834764831845f   // D^-0.5
#define LN2F 0.69314718055994530942f

__device__ __forceinline__ float bfu(unsigned u) {
  union { unsigned i; float f; } x; x.i = u << 16; return x.f;
}
__device__ __forceinline__ unsigned f2bf(float f) {
  union { float f; unsigned i; } x; x.f = f;
  unsigned r = x.i + 0x7fffu + ((x.i >> 16) & 1u);
  return r >> 16;
}
__device__ __forceinline__ void gl_lds16(const void* g, void* l) {
  __builtin_amdgcn_global_load_lds(
      (const __attribute__((address_space(1))) unsigned int*)g,
      (__attribute__((address_space(3))) unsigned int*)l, 16, 0, 0);
}

// ---------------------------------------------------------------------------
// prep2: packA (8192 blocks) + packT (768) + fuseF (64) + zero snorm (1).
// Register-capped: launch_bounds(256,4) => <=128 VGPR.
// ---------------------------------------------------------------------------
__global__ __launch_bounds__(256, 4) void prep2_kernel(
    const float* __restrict__ query, const float* __restrict__ value,
    const float* __restrict__ Wq, const float* __restrict__ Wv,
    const float* __restrict__ Wo, const float* __restrict__ bq,
    const float* __restrict__ hw,
    ushort_t* __restrict__ qh, ushort_t* __restrict__ vh,
    ushort_t* __restrict__ WqT, ushort_t* __restrict__ WvT,
    ushort_t* __restrict__ WoT, float* __restrict__ F,
    float* __restrict__ cvec, float* __restrict__ snorm)
{
  __shared__ float plds[4160];
  const int bid = blockIdx.x, tid = threadIdx.x;
  if (bid < 8192) {                     // ---- packA ----
    const float* src = (bid < 4096) ? query : value;
    ushort_t* dst = (bid < 4096) ? qh : vh;
    int i = ((bid & 4095) * 256 + tid) * 4;
    float4 x = *(const float4*)&src[i];
    uint2 oh;
    oh.x = f2bf(x.x) | (f2bf(x.y) << 16);
    oh.y = f2bf(x.z) | (f2bf(x.w) << 16);
    *(uint2*)&dst[i] = oh;
  } else if (bid < 8960) {              // ---- packT ----
    int idx = bid - 8192;
    const float* in = (idx < 256) ? Wq : (idx < 512) ? Wv : Wo;
    ushort_t* hi = (idx < 256) ? WqT : (idx < 512) ? WvT : WoT;
    int tile = idx & 255;
    int n0 = (tile & 15) * 64, k0 = (tile >> 4) * 64;
    float (*t64)[65] = (float(*)[65])plds;
    const int tr = tid >> 4, tc4 = (tid & 15) * 4;
#pragma unroll
    for (int rr = 0; rr < 64; rr += 16)
      *(float4*)&t64[tr + rr][tc4] = *(const float4*)&in[(size_t)(k0 + tr + rr) * E_DIM + n0 + tc4];
    __syncthreads();
#pragma unroll
    for (int rr = 0; rr < 64; rr += 16) {
      int n = n0 + tr + rr;
      uint2 oh;
      oh.x = f2bf(t64[tc4 + 0][tr + rr]) | (f2bf(t64[tc4 + 1][tr + rr]) << 16);
      oh.y = f2bf(t64[tc4 + 2][tr + rr]) | (f2bf(t64[tc4 + 3][tr + rr]) << 16);
      *(uint2*)&hi[(size_t)n * E_DIM + k0 + tc4] = oh;
    }
  } else if (bid < 9024) {              // ---- fuseF ----
    float* wl = plds;                   // [512]
    const int rh = (bid - 8960) & 15, h = rh & 7;
    const int e = ((bid - 8960) >> 4) * 256 + tid;
    for (int i = tid; i < 512; i += 256) wl[i] = hw[rh * 512 + i];
    __syncthreads();
    const float* wr = Wq + (size_t)e * E_DIM + h * D_DIM;
    float a0 = 0.f, a1 = 0.f, a2 = 0.f, a3 = 0.f;
#pragma unroll 2
    for (int d = 0; d < 128; d += 2) {
      float2 q2 = *(const float2*)&wr[d];
      float4 w0 = *(const float4*)&wl[d * 4];
      float4 w1 = *(const float4*)&wl[d * 4 + 4];
      a0 += q2.x * w0.x + q2.y * w1.x;
      a1 += q2.x * w0.y + q2.y * w1.y;
      a2 += q2.x * w0.z + q2.y * w1.z;
      a3 += q2.x * w0.w + q2.y * w1.w;
    }
    float4 o; o.x = a0; o.y = a1; o.z = a2; o.w = a3;
    *(float4*)&F[(size_t)e * 64 + rh * 4] = o;
    if ((bid - 8960) < 16 && tid < 4) {
      float acc = 0.f;
#pragma unroll 1
      for (int d = 0; d < 128; ++d) acc += bq[h * D_DIM + d] * wl[d * 4 + tid];
      cvec[rh * 4 + tid] = acc;
    }
  } else {                              // ---- zero snorm ----
    float4 z4 = {0.f, 0.f, 0.f, 0.f};
#pragma unroll
    for (int i = 0; i < 4; ++i)
      *(float4*)&snorm[(i * 256 + tid) * 4] = z4;
  }
}

// ---------------------------------------------------------------------------
// hashlin v2: block = 16 rows x 64 cols, K split across 4 waves (256 k each).
// 128-k LDS chunks: As[k][16] (8KB) + Fs[k][64] (32KB). Thread = 4x4 register
// tile -> 2 ds_read_b128 per 16 FMA (was 2 LDS per 4 FMA). Cross-wave
// reduction in red[] then per-thread argmax over [lin,-lin].
// ---------------------------------------------------------------------------
__global__ __launch_bounds__(256) void hashlin_kernel(const float* __restrict__ query,
                                                      const float* __restrict__ F,
                                                      const float* __restrict__ cvec,
                                                      int* __restrict__ hashb)
{
  __shared__ float As[128 * 16];
  __shared__ float Fs[128 * 64];
  __shared__ float red[4 * 16 * 64];
  const int tid = threadIdx.x;
  const int w = tid >> 6, lane = tid & 63;
  const int ty = lane >> 4, tx = lane & 15;   // rows ty*4..+3, cols tx*4..+3
  const int r0 = blockIdx.x * 16;

  float acc[4][4] = {};

  for (int kc = 0; kc < E_DIM; kc += 128) {
    __syncthreads();
    {   // stage As [k][row]: thread (row=tid>>4, kq=tid&15) reads 8 k
      int row = tid >> 4, kq = tid & 15;
      const float* src = &query[(size_t)(r0 + row) * E_DIM + kc + kq * 8];
      float4 a0 = *(const float4*)src;
      float4 a1 = *(const float4*)(src + 4);
      As[(kq * 8 + 0) * 16 + row] = a0.x; As[(kq * 8 + 1) * 16 + row] = a0.y;
      As[(kq * 8 + 2) * 16 + row] = a0.z; As[(kq * 8 + 3) * 16 + row] = a0.w;
      As[(kq * 8 + 4) * 16 + row] = a1.x; As[(kq * 8 + 5) * 16 + row] = a1.y;
      As[(kq * 8 + 6) * 16 + row] = a1.z; As[(kq * 8 + 7) * 16 + row] = a1.w;
    }
    {   // stage Fs [k][col] linear copy: 32 floats/thread
#pragma unroll
      for (int u = 0; u < 4; ++u) {
        int i = u * 2048 + tid * 8;
        float4 f0 = *(const float4*)&F[(size_t)kc * 64 + i];
        float4 f1 = *(const float4*)&F[(size_t)kc * 64 + i + 4];
        *(float4*)&Fs[i] = f0;
        *(float4*)&Fs[i + 4] = f1;
      }
    }
    __syncthreads();
    const int kbase = w * 32;
#pragma unroll
    for (int kk = 0; kk < 32; ++kk) {
      float4 av = *(const float4*)&As[(kbase + kk) * 16 + ty * 4];
      float4 fv = *(const float4*)&Fs[(kbase + kk) * 64 + tx * 4];
      const float aa[4] = {av.x, av.y, av.z, av.w};
      const float ff[4] = {fv.x, fv.y, fv.z, fv.w};
#pragma unroll
      for (int i = 0; i < 4; ++i)
#pragma unroll
        for (int j = 0; j < 4; ++j) acc[i][j] += aa[i] * ff[j];
    }
  }
  __syncthreads();
#pragma unroll
  for (int i = 0; i < 4; ++i)
#pragma unroll
    for (int j = 0; j < 4; ++j)
      red[(w * 16 + ty * 4 + i) * 64 + tx * 4 + j] = acc[i][j];
  __syncthreads();
  {   // thread -> (row = tid>>4, rh = tid&15)
    const int row = tid >> 4, rh = tid & 15;
    float lin[4];
#pragma unroll
    for (int n = 0; n < 4; ++n) {
      int col = rh * 4 + n;
      lin[n] = red[(0 * 16 + row) * 64 + col] + red[(1 * 16 + row) * 64 + col] +
               red[(2 * 16 + row) * 64 + col] + red[(3 * 16 + row) * 64 + col] +
               cvec[col];
    }
    float best = lin[0]; int bi = 0;
#pragma unroll
    for (int idx = 1; idx < 8; ++idx) {
      float v = (idx < 4) ? lin[idx] : -lin[idx - 4];
      if (v > best) { best = v; bi = idx; }   // first-occurrence argmax
    }
    int grow = r0 + row;            // t*B + b
    int t = grow >> 1, b = grow & 1;
    int rr = rh >> 3, hh = rh & 7;
    hashb[(size_t)((b * R_DIM + rr) * H_DIM + hh) * T_DIM + t] = bi;
  }
}

// ---------------------------------------------------------------------------
// MFMA GEMM 4096x1024x1024, tile 128x128, BK=64 as two 32-subtiles per
// barrier pair (halves barrier count vs r7), gl_lds(16B) staging.
// z selects problem. Cb!=null -> bf16 out (+row sumsq to snorm), else fp32.
// ---------------------------------------------------------------------------
__global__ __launch_bounds__(256) void gemm_mfma(
    const ushort_t* __restrict__ A0, const ushort_t* __restrict__ B0,
    const float* __restrict__ bias0, ushort_t* __restrict__ Cb0, float* __restrict__ Cf0,
    const ushort_t* __restrict__ A1, const ushort_t* __restrict__ B1,
    const float* __restrict__ bias1, ushort_t* __restrict__ Cb1, float* __restrict__ Cf1,
    float* __restrict__ snorm, int do_norm)
{
  const ushort_t* Ah = blockIdx.z ? A1 : A0;
  const ushort_t* Bh = blockIdx.z ? B1 : B0;
  const float* bias = blockIdx.z ? bias1 : bias0;
  ushort_t* Cb = blockIdx.z ? Cb1 : Cb0;
  float* Cf = blockIdx.z ? Cf1 : Cf0;

  __shared__ ushort_t As[2][128 * 32];
  __shared__ ushort_t Bs[2][128 * 32];
  const int tid = threadIdx.x, w = tid >> 6, lane = tid & 63;
  const int lm = lane & 15, quad = lane >> 4;
  const int wr = w >> 1, wc = w & 1;
  const int m0 = blockIdx.y * 128, n0 = blockIdx.x * 128;
  const int lrow = lane >> 2, lcol = (lane & 3) * 8;

  f32x4 acc[4][4] = {};

  for (int k0 = 0; k0 < E_DIM; k0 += 64) {
    __syncthreads();
#pragma unroll
    for (int s = 0; s < 2; ++s) {
#pragma unroll
      for (int k = 0; k < 8; ++k) {
        if ((k & 3) == w) {
          gl_lds16(Ah + (size_t)(m0 + k * 16 + lrow) * E_DIM + k0 + s * 32 + lcol, &As[s][k * 512]);
          gl_lds16(Bh + (size_t)(n0 + k * 16 + lrow) * E_DIM + k0 + s * 32 + lcol, &Bs[s][k * 512]);
        }
      }
    }
    __syncthreads();
#pragma unroll
    for (int s = 0; s < 2; ++s) {
      bf16x8 av[4], bv[4];
#pragma unroll
      for (int i = 0; i < 4; ++i) av[i] = *(const bf16x8*)&As[s][(wr * 64 + i * 16 + lm) * 32 + quad * 8];
#pragma unroll
      for (int j = 0; j < 4; ++j) bv[j] = *(const bf16x8*)&Bs[s][(wc * 64 + j * 16 + lm) * 32 + quad * 8];
#pragma unroll
      for (int i = 0; i < 4; ++i)
#pragma unroll
        for (int j = 0; j < 4; ++j)
          acc[i][j] = __builtin_amdgcn_mfma_f32_16x16x32_bf16(av[i], bv[j], acc[i][j], 0, 0, 0);
    }
  }

  float rs[4][4] = {};
#pragma unroll
  for (int j = 0; j < 4; ++j) {
    int col = n0 + wc * 64 + j * 16 + lm;
    float bj = bias[col];
#pragma unroll
    for (int i = 0; i < 4; ++i) {
      int rowb = m0 + wr * 64 + i * 16 + quad * 4;
#pragma unroll
      for (int rg = 0; rg < 4; ++rg) {
        float val = acc[i][j][rg] + bj;
        if (Cb) {
          unsigned ub = f2bf(val);
          Cb[(size_t)(rowb + rg) * E_DIM + col] = (ushort_t)ub;
          float vb = bfu(ub);
          rs[i][rg] += vb * vb;
        } else {
          Cf[(size_t)(rowb + rg) * E_DIM + col] = val;
        }
      }
    }
  }
  if (do_norm && blockIdx.z == 0) {
#pragma unroll
    for (int i = 0; i < 4; ++i)
#pragma unroll
      for (int rg = 0; rg < 4; ++rg) {
        float s = rs[i][rg];
        s += __shfl_xor(s, 1);
        s += __shfl_xor(s, 2);
        s += __shfl_xor(s, 4);
        s += __shfl_xor(s, 8);
        if (lm == 0)
          atomicAdd(&snorm[m0 + wr * 64 + i * 16 + quad * 4 + rg], s);
      }
  }
}

// ---------------------------------------------------------------------------
// Stable counting sort by hash in [0,8) per (b,r,h). Parallel scan. 32 blocks.
// ---------------------------------------------------------------------------
__global__ __launch_bounds__(256) void sort_kernel(const int* __restrict__ hashb,
                                                   int* __restrict__ p, int* __restrict__ inv)
{
  const int bid = blockIdx.x, tid = threadIdx.x;
  const int lane = tid & 63, w = tid >> 6;
  const int* hrow = hashb + (size_t)bid * T_DIM;
  __shared__ int mat[8][256];
  __shared__ int btot[8], bbase[8];
  int cnt[8];
#pragma unroll
  for (int v = 0; v < 8; ++v) cnt[v] = 0;
  int hv[8];
#pragma unroll
  for (int j = 0; j < 8; ++j) { hv[j] = hrow[tid * 8 + j]; cnt[hv[j]]++; }
#pragma unroll
  for (int v = 0; v < 8; ++v) mat[v][tid] = cnt[v];
  __syncthreads();
  for (int v = w; v < 8; v += 4) {
    int4 c4 = *(const int4*)&mat[v][lane * 4];
    int s = c4.x + c4.y + c4.z + c4.w;
    int x = s;
    for (int off = 1; off < 64; off <<= 1) {
      int y = __shfl_up(x, off);
      if (lane >= off) x += y;
    }
    int excl = x - s;
    mat[v][lane * 4 + 0] = excl;
    mat[v][lane * 4 + 1] = excl + c4.x;
    mat[v][lane * 4 + 2] = excl + c4.x + c4.y;
    mat[v][lane * 4 + 3] = excl + c4.x + c4.y + c4.z;
    if (lane == 63) btot[v] = x;
  }
  __syncthreads();
  if (tid == 0) {
    int run = 0;
    for (int v = 0; v < 8; ++v) { bbase[v] = run; run += btot[v]; }
  }
  __syncthreads();
#pragma unroll
  for (int v = 0; v < 8; ++v) cnt[v] = 0;
#pragma unroll
  for (int j = 0; j < 8; ++j) {
    int v = hv[j];
    int pos = bbase[v] + mat[v][tid] + cnt[v];
    cnt[v]++;
    p[(size_t)bid * T_DIM + pos] = tid * 8 + j;
    inv[(size_t)bid * T_DIM + tid * 8 + j] = pos;
  }
}

// ---------------------------------------------------------------------------
// gather: per (c, brh): meta/invn in sorted order; ksort padded bf16 rows
// [pos][136]; vt transposed chunk tiles [d][32]. invn = 1/sqrt(snorm).
// ---------------------------------------------------------------------------
__global__ __launch_bounds__(256) void gather_kernel(
    const ushort_t* __restrict__ qfb, const ushort_t* __restrict__ vfb,
    const float* __restrict__ snorm, const int* __restrict__ hashb,
    const int* __restrict__ p, const int* __restrict__ inv,
    int* __restrict__ meta_s, float* __restrict__ invn_s,
    ushort_t* __restrict__ ksort, ushort_t* __restrict__ vt)
{
  const int c = blockIdx.x, brh = blockIdx.y;
  const int b = brh >> 4, h = brh & 7;
  const int brh_o = brh ^ 8;
  const int tid = threadIdx.x;
  __shared__ int ts[32];
  __shared__ ushort_t vtile[32 * 136];

  if (tid < 32) {
    int pos = c * 32 + tid;
    int t = p[(size_t)brh * T_DIM + pos];
    int hh = hashb[(size_t)brh * T_DIM + t];
    int co = inv[(size_t)brh_o * T_DIM + t] >> 5;
    meta_s[(size_t)brh * T_DIM + pos] = t | (hh << 11) | (co << 14);
    invn_s[(size_t)brh * T_DIM + pos] = 1.0f / sqrtf(snorm[t * B_DIM + b]);
    ts[tid] = t;
  }
  __syncthreads();
  {
    int i = tid >> 3, part = tid & 7;
    int t = ts[i];
    const ushort_t* src = qfb + ((size_t)(t * B_DIM + b) << 10) + h * D_DIM + part * 16;
    uint4 a = *(const uint4*)src;
    uint4 bb = *(const uint4*)(src + 8);
    ushort_t* dst = ksort + ((size_t)brh * T_DIM + c * 32 + i) * 136 + part * 16;
    *(uint4*)dst = a; *(uint4*)(dst + 8) = bb;
    const ushort_t* vsrc = vfb + ((size_t)(t * B_DIM + b) << 10) + h * D_DIM + part * 16;
    uint4 va = *(const uint4*)vsrc;
    uint4 vb = *(const uint4*)(vsrc + 8);
    ushort_t* vdst = &vtile[i * 136 + part * 16];
    *(uint4*)vdst = va; *(uint4*)(vdst + 8) = vb;
  }
  __syncthreads();
  {
    int d = tid >> 1, half = tid & 1;
    unsigned pk[8];
#pragma unroll
    for (int jj = 0; jj < 8; ++jj) {
      unsigned lo = vtile[(half * 16 + jj * 2) * 136 + d];
      unsigned hi = vtile[(half * 16 + jj * 2 + 1) * 136 + d];
      pk[jj] = lo | (hi << 16);
    }
    ushort_t* out = vt + ((size_t)(brh * 64 + c)) * 4096 + d * 32 + half * 16;
    uint4 o0; o0.x = pk[0]; o0.y = pk[1]; o0.z = pk[2]; o0.w = pk[3];
    uint4 o1; o1.x = pk[4]; o1.y = pk[5]; o1.z = pk[6]; o1.w = pk[7];
    *(uint4*)out = o0; *(uint4*)(out + 8) = o1;
  }
}

// ---------------------------------------------------------------------------
// attn: block per (c,h,b*2+r). All staging via global_load_lds from presorted
// ksort / vt. Q = middle 32 rows of K window. Scaling folded into epilogue.
// ---------------------------------------------------------------------------
__global__ __launch_bounds__(256) void attn_kernel(
    const ushort_t* __restrict__ ksort, const ushort_t* __restrict__ vt,
    const int* __restrict__ meta_s, const float* __restrict__ invn_s,
    ushort_t* __restrict__ o_out, float* __restrict__ z_out)
{
  const int c = blockIdx.x, h = blockIdx.y, bz = blockIdx.z;
  const int b = bz >> 1, r = bz & 1;
  const int brh = (b * R_DIM + r) * H_DIM + h;
  const int tid = threadIdx.x;
  const int lane = tid & 63, w = tid >> 6;
  const int lm = lane & 15, quad = lane >> 4;

  // Kw[96][136]us @0 (26112 B); VT 3x[128][32]us @26112 (24576 B)
  // SS[32][100]f32 overlays @0; Ps[32][104]us @13312.
  __shared__ __align__(16) unsigned char smem[50688];
  ushort_t* Kw = (ushort_t*)smem;
  ushort_t* VTb = (ushort_t*)(smem + 26112);
  float*    SS = (float*)smem;
  ushort_t* Ps = (ushort_t*)(smem + 13312);
  __shared__ int skp[M_WIN];
  __shared__ float s_invn[M_WIN];

  int cjs[3] = {(c + 63) & 63, c, (c + 1) & 63};

  // --- bulk DMA staging (no VALU conversions) ---
  int cnt = 0;
#pragma unroll
  for (int j = 0; j < 3; ++j) {
    const ushort_t* gk = ksort + ((size_t)brh * T_DIM + cjs[j] * 32) * 136;
    ushort_t* lk = Kw + j * 4352;
#pragma unroll
    for (int k = 0; k < 8; ++k) {
      if ((cnt++ & 3) == w) gl_lds16(gk + k * 512 + lane * 8, lk + k * 512);
    }
    if ((cnt++ & 3) == w) {            // 512-B remainder of the 8704-B chunk
      if (lane < 32) gl_lds16(gk + 4096 + lane * 8, lk + 4096);
    }
  }
#pragma unroll
  for (int j = 0; j < 3; ++j) {
    const ushort_t* gv = vt + ((size_t)(brh * 64 + cjs[j])) * 4096;
    ushort_t* lv = VTb + j * 4096;
#pragma unroll
    for (int k = 0; k < 8; ++k) {
      if ((cnt++ & 3) == w) gl_lds16(gv + k * 512 + lane * 8, lv + k * 512);
    }
  }
  if (tid < M_WIN) {
    int pos = cjs[tid >> 5] * 32 + (tid & 31);
    skp[tid] = meta_s[(size_t)brh * T_DIM + pos];
    s_invn[tid] = invn_s[(size_t)brh * T_DIM + pos];
  }
  __syncthreads();   // drains gl_lds (vmcnt) + meta

  // --- QK^T MFMA: wave w -> m-tile (w&1), n-tiles (w>>1)*3+{0,1,2} ---
  const int mw = w & 1, nset = w >> 1;
  bf16x8 av[4];
#pragma unroll
  for (int kk = 0; kk < 4; ++kk)
    av[kk] = *(const bf16x8*)&Kw[(32 + mw * 16 + lm) * 136 + kk * 32 + quad * 8];
  f32x4 sacc[3] = {};
#pragma unroll
  for (int jj = 0; jj < 3; ++jj) {
    int nt = nset * 3 + jj;
#pragma unroll
    for (int kk = 0; kk < 4; ++kk) {
      bf16x8 bv = *(const bf16x8*)&Kw[(nt * 16 + lm) * 136 + kk * 32 + quad * 8];
      sacc[jj] = __builtin_amdgcn_mfma_f32_16x16x32_bf16(av[kk], bv, sacc[jj], 0, 0, 0);
    }
  }
  __syncthreads();   // Kw reads done; SS overlay safe

  // --- epilogue: scale + masks -> SS ---
  const int rowb = mw * 16 + quad * 4;
#pragma unroll
  for (int jj = 0; jj < 3; ++jj) {
    int col = (nset * 3 + jj) * 16 + lm;
    int kp = skp[col];
    float scl = SCALING * s_invn[col];
#pragma unroll
    for (int rg = 0; rg < 4; ++rg) {
      int qp = skp[32 + rowb + rg];
      float sc = sacc[jj][rg] * scl;
      if ((kp ^ qp) & 0x3800) sc -= 1.0e16f;       // mask_different_hashes
      if (!((kp ^ qp) & 0x7FF)) sc -= 1.0e8f;      // mask_current
      int dc = ((kp >> 14) - (qp >> 14)) & 63;
      if (dc <= 1 || dc == 63) sc -= LN2F;         // -log(dup)
      SS[(rowb + rg) * 100 + col] = sc;
    }
  }
  __syncthreads();

  // --- softmax (8 threads/row) -> Ps bf16, z ---
  {
    const int l = tid >> 3, g = tid & 7;
    float smy[12];
#pragma unroll
    for (int j = 0; j < 12; ++j) smy[j] = SS[l * 100 + g + 8 * j];
    float mx = smy[0];
#pragma unroll
    for (int j = 1; j < 12; ++j) mx = fmaxf(mx, smy[j]);
    mx = fmaxf(mx, __shfl_xor(mx, 1));
    mx = fmaxf(mx, __shfl_xor(mx, 2));
    mx = fmaxf(mx, __shfl_xor(mx, 4));
    float sum = 0.f, ey[12];
#pragma unroll
    for (int j = 0; j < 12; ++j) { ey[j] = expf(smy[j] - mx); sum += ey[j]; }
    sum += __shfl_xor(sum, 1);
    sum += __shfl_xor(sum, 2);
    sum += __shfl_xor(sum, 4);
    float inv_s = 1.0f / sum;
#pragma unroll
    for (int j = 0; j < 12; ++j)
      Ps[l * 104 + g + 8 * j] = (ushort_t)f2bf(ey[j] * inv_s);
    if (g == 0) z_out[(size_t)brh * T_DIM + (skp[32 + l] & 2047)] = mx + logf(sum);
  }
  __syncthreads();

  // --- PV MFMA: wave w -> m-tile (w&1), d-tiles (w>>1)*4+{0..3}; K=96 ---
  const int dset = w >> 1;
  bf16x8 pa[3];
#pragma unroll
  for (int kk = 0; kk < 3; ++kk)
    pa[kk] = *(const bf16x8*)&Ps[(mw * 16 + lm) * 104 + kk * 32 + quad * 8];
  f32x4 oacc[4] = {};
#pragma unroll
  for (int jj = 0; jj < 4; ++jj) {
    int dt = dset * 4 + jj;
#pragma unroll
    for (int kk = 0; kk < 3; ++kk) {
      const ushort_t* VTk = VTb + kk * 4096;
      bf16x8 bv = *(const bf16x8*)&VTk[(dt * 16 + lm) * 32 + quad * 8];
      oacc[jj] = __builtin_amdgcn_mfma_f32_16x16x32_bf16(pa[kk], bv, oacc[jj], 0, 0, 0);
    }
  }
#pragma unroll
  for (int jj = 0; jj < 4; ++jj) {
    int col = (dset * 4 + jj) * 16 + lm;
#pragma unroll
    for (int rg = 0; rg < 4; ++rg) {
      int tqo = skp[32 + rowb + rg] & 2047;
      o_out[((size_t)brh * T_DIM + tqo) * D_DIM + col] = (ushort_t)f2bf(oacc[jj][rg]);
    }
  }
}

// ---------------------------------------------------------------------------
// Combine rounds (bf16 o) -> ctx bf16.
// ---------------------------------------------------------------------------
__global__ __launch_bounds__(256) void combine_kernel(const ushort_t* __restrict__ obf,
                                                      const float* __restrict__ z_buf,
                                                      ushort_t* __restrict__ ctx)
{
  int gid = blockIdx.x * 256 + threadIdx.x;   // [0, 1048576)
  int d4 = gid & 31;
  int t = (gid >> 5) & (T_DIM - 1);
  int h = (gid >> 16) & 7;
  int b = gid >> 19;
  int brh0 = (b * R_DIM + 0) * H_DIM + h;
  int brh1 = brh0 + H_DIM;
  float z0 = z_buf[(size_t)brh0 * T_DIM + t], z1 = z_buf[(size_t)brh1 * T_DIM + t];
  float mz = fmaxf(z0, z1);
  float e0 = expf(z0 - mz), e1 = expf(z1 - mz);
  float is = 1.0f / (e0 + e1);
  float w0 = e0 * is, w1 = e1 * is;
  uint2 a = *(const uint2*)&obf[((size_t)brh0 * T_DIM + t) * D_DIM + d4 * 4];
  uint2 cc = *(const uint2*)&obf[((size_t)brh1 * T_DIM + t) * D_DIM + d4 * 4];
  uint2 o;
  o.x = f2bf(w0 * bfu(a.x & 0xffffu) + w1 * bfu(cc.x & 0xffffu)) |
        (f2bf(w0 * bfu(a.x >> 16) + w1 * bfu(cc.x >> 16)) << 16);
  o.y = f2bf(w0 * bfu(a.y & 0xffffu) + w1 * bfu(cc.y & 0xffffu)) |
        (f2bf(w0 * bfu(a.y >> 16) + w1 * bfu(cc.y >> 16)) << 16);
  *(uint2*)&ctx[((size_t)(t * B_DIM + b) << 10) + h * D_DIM + d4 * 4] = o;
}

// ---------------------------------------------------------------------------
extern "C" void kernel_launch(void* const* d_in, const int* in_sizes, int n_in,
                              void* d_out, int out_size, void* d_ws, size_t ws_size,
                              hipStream_t stream)
{
  const float* query = (const float*)d_in[0];
  // d_in[1] = key, unused (share_kq)
  const float* value = (const float*)d_in[2];
  const float* Wq = (const float*)d_in[3];
  const float* bq = (const float*)d_in[4];
  const float* Wv = (const float*)d_in[5];
  const float* bv = (const float*)d_in[6];
  const float* Wo = (const float*)d_in[7];
  const float* bo = (const float*)d_in[8];
  const float* hw = (const float*)d_in[9];

  float* ws = (float*)d_ws;
  ushort_t* qh    = (ushort_t*)ws;               // 4,194,304 us
  ushort_t* vh    = qh + 4194304;                // 4,194,304 us
  ushort_t* obuf  = qh;                          // overlay (dead after gemm z=2)
  ushort_t* qfb   = (ushort_t*)(ws + 4194304);   // 4,194,304 us
  ushort_t* ctx   = qfb;                         // overlay (qfb dead after gather)
  ushort_t* vfb   = qfb + 4194304;               // 4,194,304 us
  ushort_t* ksort = vfb + 4194304;               // 8,912,896 us
  ushort_t* vt    = ksort + 8912896;             // 8,388,608 us
  ushort_t* WqTh  = vt + 8388608;                // 1,048,576 us x3
  ushort_t* WvTh  = WqTh + 1048576;
  ushort_t* WoTh  = WvTh + 1048576;
  float* F        = (float*)(WoTh + 1048576);    // 65,536 f
  float* cvec     = F + 65536;                   // 64 f
  float* zbuf     = cvec + 64;                   // 65,536 f
  float* snorm    = zbuf + 65536;                // 4,096 f
  int* hashb      = (int*)(snorm + 4096);        // 65,536 i
  int* pperm      = hashb + 65536;
  int* pinv       = pperm + 65536;
  int* meta_s     = pinv + 65536;
  float* invn_s   = (float*)(meta_s + 65536);

  prep2_kernel<<<9025, 256, 0, stream>>>(query, value, Wq, Wv, Wo, bq, hw,
                                         qh, vh, WqTh, WvTh, WoTh, F, cvec, snorm);
  hashlin_kernel<<<256, 256, 0, stream>>>(query, F, cvec, hashb);
  gemm_mfma<<<dim3(8, 32, 2), 256, 0, stream>>>(qh, WqTh, bq, qfb, (float*)nullptr,
                                                vh, WvTh, bv, vfb, (float*)nullptr,
                                                snorm, 1);
  sort_kernel<<<32, 256, 0, stream>>>(hashb, pperm, pinv);
  gather_kernel<<<dim3(64, 32), 256, 0, stream>>>(qfb, vfb, snorm, hashb, pperm, pinv,
                                                  meta_s, invn_s, ksort, vt);
  attn_kernel<<<dim3(64, 8, 4), 256, 0, stream>>>(ksort, vt, meta_s, invn_s, obuf, zbuf);
  combine_kernel<<<4096, 256, 0, stream>>>(obuf, zbuf, ctx);
  gemm_mfma<<<dim3(8, 32, 1), 256, 0, stream>>>(ctx, WoTh, bo, (ushort_t*)nullptr, (float*)d_out,
                                                (const ushort_t*)nullptr, (const ushort_t*)nullptr,
                                                (const float*)nullptr, (ushort_t*)nullptr, (float*)nullptr,
                                                snorm, 0);
}